// Round 9
// baseline (108.582 us; speedup 1.0000x reference)
//
#include <hip/hip_runtime.h>
#include <hip/hip_bf16.h>
#include <stdint.h>

#define B_    8
#define CIN   64
#define COUT  64
#define NPATH 9
#define H_    128
#define W_    128
#define HW    16384
#define PTOT  131072   // B*H*W
#define NBIN  72       // NPATH * B_
#define CHUNK 32       // pixels per chunk
#define NBLK  512      // persistent k_conv blocks (2 per CU)
#define MAXCHUNK 8192

typedef float  f32x4  __attribute__((ext_vector_type(4)));
typedef __bf16 bf16x8 __attribute__((ext_vector_type(8)));
typedef short  short8 __attribute__((ext_vector_type(8)));
typedef unsigned short ushort4v __attribute__((ext_vector_type(4)));

__device__ __forceinline__ short f2bf(float f) {
    __bf16 b = (__bf16)f;
    return __builtin_bit_cast(short, b);
}
__device__ __forceinline__ float bf2f(unsigned short u) {
    unsigned v = ((unsigned)u) << 16;
    return __builtin_bit_cast(float, v);
}
__device__ __forceinline__ float fast_tanh(float a) {
    // tanh(a) = 1 - 2/(exp2(2a*log2e)+1); saturates correctly at +-inf
    float e = __builtin_amdgcn_exp2f(a * 2.885390081777927f);
    return 1.0f - 2.0f / (e + 1.0f);
}

// ---------------------------------------------------------------- K1 (fused):
// blocks 0..255:  x-tile in LDS, 2 px/thread: fp32 observer scores + argmax +
//                 compaction + Xb bf16 NHWC emit
// blocks 256..336: kernels_w -> WbF MFMA-fragment order
__global__ __launch_bounds__(256) void k_pre(
                      const float* __restrict__ x,
                      const float* __restrict__ w1, const float* __restrict__ b1,
                      const float* __restrict__ w2, const float* __restrict__ b2,
                      const float* __restrict__ kw,
                      unsigned* __restrict__ gcnt, unsigned* __restrict__ lists,
                      unsigned short* __restrict__ Xb,
                      unsigned short* __restrict__ WbF) {
    int t = threadIdx.x;
    if (blockIdx.x >= 256) {
        int ob = ((int)blockIdx.x - 256) * 4096 + t * 16;
        #pragma unroll
        for (int j = 0; j < 16; ++j) {
            int o = ob + j;
            int jj   = o & 7;
            int lane = (o >> 3) & 63;
            int f    = (o >> 9) & 3;
            int rest = o >> 11;
            int s    = rest % 18;
            int n    = rest / 18;
            int c    = f * 16 + (lane & 15);
            int kg   = lane >> 4;
            int ci   = ((s & 1) << 5) + (kg << 3) + jj;
            int tap  = s >> 1;
            WbF[o] = (unsigned short)f2bf(kw[((n * 64 + c) * 64 + ci) * 9 + tap]);
        }
        return;
    }
    __shared__ float tile[64 * 512];   // 128 KB, [ch][px]
    __shared__ float sw1[2048];        // [32][64]
    __shared__ float sw2[288];         // [9][32]
    __shared__ float sb1[32];
    __shared__ float sb2[9];
    __shared__ unsigned scnt[NBIN];
    __shared__ unsigned sbase[NBIN];
    int wid = t >> 6, lane = t & 63;
    int px0 = blockIdx.x * 512;        // GLOBAL pixel base (for Xb / lists)
    int hwb = px0 & 16383;             // within-batch offset (for x reads)
    int b = blockIdx.x >> 5;

    // ---- async stage x tile: wave wid stages channels wid*16..+15
    #pragma unroll
    for (int k = 0; k < 16; ++k) {
        int ch = wid * 16 + k;
        const float* src = x + (((size_t)(b * 64 + ch)) << 14) + hwb;
        #pragma unroll
        for (int hf = 0; hf < 2; ++hf)
            __builtin_amdgcn_global_load_lds(
                (const __attribute__((address_space(1))) unsigned int*)(src + hf * 256 + lane * 4),
                (__attribute__((address_space(3))) unsigned int*)((char*)tile + ch * 2048 + hf * 1024 + lane * 16),
                16, 0, 0);
    }
    #pragma unroll
    for (int i = 0; i < 8; ++i) sw1[t + i * 256] = w1[t + i * 256];
    for (int i = t; i < 288; i += 256) sw2[i] = w2[i];
    if (t < 32) sb1[t] = b1[t];
    if (t < 9)  sb2[t] = b2[t];
    if (t < NBIN) scnt[t] = 0u;
    __syncthreads();

    float h0[32], h1[32];
    #pragma unroll
    for (int j = 0; j < 32; ++j) { h0[j] = sb1[j]; h1[j] = sb1[j]; }

    unsigned short e0[8], e1[8];
    size_t xo0 = ((size_t)(px0 + t)) << 6;
    size_t xo1 = ((size_t)(px0 + 256 + t)) << 6;
    #pragma unroll
    for (int q = 0; q < 16; ++q) {
        float a0 = tile[(q * 4 + 0) * 512 + t];
        float a1 = tile[(q * 4 + 1) * 512 + t];
        float a2 = tile[(q * 4 + 2) * 512 + t];
        float a3 = tile[(q * 4 + 3) * 512 + t];
        float c0 = tile[(q * 4 + 0) * 512 + 256 + t];
        float c1 = tile[(q * 4 + 1) * 512 + 256 + t];
        float c2 = tile[(q * 4 + 2) * 512 + 256 + t];
        float c3 = tile[(q * 4 + 3) * 512 + 256 + t];
        const int qo = (q & 1) * 4;
        e0[qo + 0] = (unsigned short)f2bf(a0); e0[qo + 1] = (unsigned short)f2bf(a1);
        e0[qo + 2] = (unsigned short)f2bf(a2); e0[qo + 3] = (unsigned short)f2bf(a3);
        e1[qo + 0] = (unsigned short)f2bf(c0); e1[qo + 1] = (unsigned short)f2bf(c1);
        e1[qo + 2] = (unsigned short)f2bf(c2); e1[qo + 3] = (unsigned short)f2bf(c3);
        if (q & 1) {
            short8 v0, v1;
            #pragma unroll
            for (int i = 0; i < 8; ++i) { v0[i] = (short)e0[i]; v1[i] = (short)e1[i]; }
            *(short8*)(Xb + xo0 + (q >> 1) * 8) = v0;
            *(short8*)(Xb + xo1 + (q >> 1) * 8) = v1;
        }
        #pragma unroll
        for (int j = 0; j < 32; ++j) {
            const f32x4 wv4 = *(const f32x4*)&sw1[j * 64 + q * 4];
            h0[j] += a0 * wv4[0] + a1 * wv4[1] + a2 * wv4[2] + a3 * wv4[3];
            h1[j] += c0 * wv4[0] + c1 * wv4[1] + c2 * wv4[2] + c3 * wv4[3];
        }
    }

    float s0[9], s1[9];
    #pragma unroll
    for (int nn = 0; nn < 9; ++nn) { s0[nn] = sb2[nn]; s1[nn] = sb2[nn]; }
    #pragma unroll
    for (int j = 0; j < 32; ++j) {
        float t0 = fast_tanh(h0[j]);
        float t1 = fast_tanh(h1[j]);
        #pragma unroll
        for (int nn = 0; nn < 9; ++nn) {
            float wv = sw2[nn * 32 + j];
            s0[nn] += t0 * wv;
            s1[nn] += t1 * wv;
        }
    }
    float b0 = s0[0], b1v = s1[0]; int i0 = 0, i1 = 0;
    #pragma unroll
    for (int nn = 1; nn < 9; ++nn) {
        if (s0[nn] > b0)  { b0 = s0[nn]; i0 = nn; }
        if (s1[nn] > b1v) { b1v = s1[nn]; i1 = nn; }
    }
    int bin0 = i0 * 8 + b, bin1 = i1 * 8 + b;
    unsigned r0 = atomicAdd(&scnt[bin0], 1u);
    unsigned r1 = atomicAdd(&scnt[bin1], 1u);
    __syncthreads();
    if (t < NBIN && scnt[t]) sbase[t] = atomicAdd(&gcnt[t], scnt[t]);
    __syncthreads();
    lists[bin0 * 16384 + sbase[bin0] + r0] = (unsigned)(px0 + t);
    lists[bin1 * 16384 + sbase[bin1] + r1] = (unsigned)(px0 + 256 + t);
}

// ---------------------------------------------------------------- K1b:
// chunkinfo[k] = bin<<32 | cnt<<16 | local_base; ctot = total chunk count
__global__ void k_prefix(const unsigned* __restrict__ gcnt,
                         unsigned long long* __restrict__ chunkinfo,
                         unsigned* __restrict__ ctot) {
    __shared__ unsigned st[NBIN + 1];
    int t = threadIdx.x;
    for (int i = t; i < MAXCHUNK; i += 256) chunkinfo[i] = ~0ull;
    if (t == 0) {
        unsigned acc = 0;
        for (int bin = 0; bin < NBIN; ++bin) {
            st[bin] = acc;
            acc += (gcnt[bin] + (CHUNK - 1u)) / CHUNK;
        }
        st[NBIN] = acc;
        *ctot = acc;
    }
    __syncthreads();
    if (t < NBIN) {
        unsigned c0 = st[t], cnt = gcnt[t];
        unsigned nch = (cnt + (CHUNK - 1u)) / CHUNK;
        for (unsigned k = 0; k < nch; ++k)
            chunkinfo[c0 + k] = ((unsigned long long)t << 32)
                              | ((unsigned long long)cnt << 16)
                              | (unsigned long long)(k * CHUNK);
    }
}

// ---------------------------------------------------------------- K2:
// persistent gathered implicit-GEMM selected conv.
// 512 blocks (2/CU) x 512 thr (8 waves). CHUNK=32 px, dbuf 2x36 KB.
// 3-stage meta pipeline: NO load is consumed in its issuing iteration.
// Per iteration each thread issues 4..5 stage + 2 lists + 1 info = 7..8 VMEM
// ops; vmcnt(7) therefore guarantees everything older (current chunk's stage)
// has landed while keeping next chunk's stage in flight.
__global__ __launch_bounds__(512, 4) void k_conv(
        const unsigned short* __restrict__ Xb, const unsigned short* __restrict__ WbF,
        const float* __restrict__ kb, const unsigned* __restrict__ lists,
        const unsigned long long* __restrict__ chunkinfo, const unsigned* __restrict__ ctot,
        unsigned short* __restrict__ Yc, float* __restrict__ sums) {
    __shared__ char blds[2][36864];
    int t = threadIdx.x;
    int wid = t >> 6, lane = t & 63, kg = lane >> 4, l15 = lane & 15;
    int f = wid & 3, gh = wid >> 2;
    int slot = t & 255, spx = slot >> 3;
    int sq8 = ((slot & 7) ^ (spx & 7)) * 8;   // swizzled source part (shorts)
    int tap0 = (t >> 8) * 5;                  // waves 0-3: taps 0-4; waves 4-7: taps 5-8
    int ntap = (t >> 8) ? 4 : 5;

    unsigned C = *ctot;
    unsigned bid = (blockIdx.x & 7) * 64 + (blockIdx.x >> 3);  // XCD-chunked swizzle
    unsigned c0 = (bid * C) / NBLK, c1 = ((bid + 1) * C) / NBLK;
    if (c0 >= c1) return;

    #define STAGE(P, BUF) do {                                                    \
        unsigned p_ = (P);                                                        \
        int h_ = (int)((p_ >> 7) & 127u), w_ = (int)(p_ & 127u);                  \
        unsigned pb_ = p_ & ~16383u;                                              \
        _Pragma("unroll")                                                         \
        for (int k_ = 0; k_ < 5; ++k_) {                                          \
            if (k_ < ntap) {                                                      \
                int tap_ = tap0 + k_;                                             \
                int dh_ = tap_ / 3 - 1, dw_ = tap_ % 3 - 1;                       \
                int h2_ = min(max(h_ + dh_, 0), 127);                             \
                int w2_ = min(max(w_ + dw_, 0), 127);                             \
                const unsigned short* s_ =                                        \
                    Xb + ((size_t)(pb_ | (unsigned)((h2_ << 7) + w2_)) << 6) + sq8; \
                __builtin_amdgcn_global_load_lds(                                 \
                    (const __attribute__((address_space(1))) unsigned int*)s_,    \
                    (__attribute__((address_space(3))) unsigned int*)((BUF) + tap_ * 4096 + slot * 16), \
                    16, 0, 0);                                                    \
            }                                                                     \
        }                                                                         \
    } while (0)

    #define DECODE(INFO, BIN, CNT, BAS) { BIN = (int)((INFO) >> 32); \
        CNT = (int)(((INFO) >> 16) & 0xFFFFu); BAS = (int)((INFO) & 0xFFFFu); }

    // ---- prologue: fill the 3-stage pipeline
    unsigned long long inf;
    int cb, cc_, cbase; unsigned cpm, cps;
    inf = chunkinfo[c0];
    DECODE(inf, cb, cc_, cbase);
    cpm = lists[cb * 16384 + min(cbase + gh * 16 + l15, cc_ - 1)];
    cps = lists[cb * 16384 + min(cbase + spx, cc_ - 1)];
    STAGE(cps, blds[0]);                       // stage chunk c0 -> buf0

    int nb, nc_, nbase; unsigned npm, nps;
    inf = chunkinfo[min(c0 + 1, c1 - 1)];
    DECODE(inf, nb, nc_, nbase);
    npm = lists[nb * 16384 + min(nbase + gh * 16 + l15, nc_ - 1)];
    nps = lists[nb * 16384 + min(nbase + spx, nc_ - 1)];
    unsigned long long inf2 = chunkinfo[min(c0 + 2, c1 - 1)];

    // weights + bias for cur bin
    int n = cb >> 3, b = cb & 7;
    short8 wv[18];
    #pragma unroll
    for (int s = 0; s < 18; ++s)
        wv[s] = *(const short8*)(WbF + n * 36864 + ((s * 4 + f) * 64 + lane) * 8);
    f32x4 bias = *(const f32x4*)(kb + n * 64 + f * 16 + kg * 4);

    int cur = 0;
    float s1[4] = {0.f,0.f,0.f,0.f}, s2[4] = {0.f,0.f,0.f,0.f};

    for (unsigned c = c0; c < c1; ++c) {
        // (1) stage chunk c+1 (ps loaded 1 iter ago)
        STAGE(nps, blds[cur ^ 1]);
        // (2) lists for chunk c+2 (info loaded 1 iter ago)
        int fb, fc_, fbase; unsigned fpm, fps;
        DECODE(inf2, fb, fc_, fbase);
        fpm = lists[fb * 16384 + min(fbase + gh * 16 + l15, fc_ - 1)];
        fps = lists[fb * 16384 + min(fbase + spx, fc_ - 1)];
        // (3) info for chunk c+3
        unsigned long long inf3 = chunkinfo[min(c + 3, c1 - 1)];

        asm volatile("s_waitcnt vmcnt(7)" ::: "memory");
        __builtin_amdgcn_sched_barrier(0);
        __builtin_amdgcn_s_barrier();

        // ---- masks for current chunk
        int valid = (cbase + gh * 16 + l15) < cc_ ? 1 : 0;
        int inb = 0;
        {
            int hh = (int)((cpm >> 7) & 127u), ww = (int)(cpm & 127u);
            #pragma unroll
            for (int tap = 0; tap < 9; ++tap) {
                int dh = tap / 3 - 1, dw = tap % 3 - 1;
                if ((unsigned)(hh + dh) < 128u && (unsigned)(ww + dw) < 128u) inb |= (1 << tap);
            }
            inb = valid ? inb : 0;
        }

        // ---- MFMA phase (A regs, B LDS)
        f32x4 acc = (f32x4)0.0f;
        const short8 zero8 = (short8)0;
        const char* bufc = blds[cur];
        int px = gh * 16 + l15;
        #pragma unroll
        for (int s = 0; s < 18; ++s) {
            const int tap = s >> 1;
            const int pr = ((s & 1) << 2) | kg;
            short8 braw = *(const short8*)(bufc + tap * 4096 + px * 128 + ((pr ^ (px & 7)) << 4));
            short8 sel = ((inb >> tap) & 1) ? braw : zero8;
            acc = __builtin_amdgcn_mfma_f32_16x16x32_bf16(
                      __builtin_bit_cast(bf16x8, wv[s]),
                      __builtin_bit_cast(bf16x8, sel), acc, 0, 0, 0);
        }

        // ---- epilogue
        {
            f32x4 o;
            #pragma unroll
            for (int r = 0; r < 4; ++r) o[r] = fmaxf(acc[r] + bias[r], 0.0f);
            if (valid) {
                ushort4v u;
                #pragma unroll
                for (int r = 0; r < 4; ++r) u[r] = (unsigned short)f2bf(o[r]);
                *(ushort4v*)(Yc + (((size_t)cpm) << 6) + f * 16 + kg * 4) = u;
            }
            #pragma unroll
            for (int r = 0; r < 4; ++r) {
                float sv = valid ? o[r] : 0.0f;
                s1[r] += sv;
                s2[r] += sv * sv;
            }
        }

        // ---- bin switch: flush stats, reload weights/bias
        if (nb != cb && c + 1 < c1) {
            float f1[4], f2[4];
            #pragma unroll
            for (int r = 0; r < 4; ++r) { f1[r] = s1[r]; f2[r] = s2[r]; s1[r] = 0.f; s2[r] = 0.f; }
            #pragma unroll
            for (int m = 1; m < 16; m <<= 1) {
                #pragma unroll
                for (int r = 0; r < 4; ++r) {
                    f1[r] += __shfl_xor(f1[r], m, 64);
                    f2[r] += __shfl_xor(f2[r], m, 64);
                }
            }
            if (l15 == 0) {
                #pragma unroll
                for (int r = 0; r < 4; ++r) {
                    int ch = f * 16 + kg * 4 + r;
                    atomicAdd(&sums[b * 64 + ch],       f1[r]);
                    atomicAdd(&sums[512 + b * 64 + ch], f2[r]);
                }
            }
            n = nb >> 3; b = nb & 7;
            #pragma unroll
            for (int s = 0; s < 18; ++s)
                wv[s] = *(const short8*)(WbF + n * 36864 + ((s * 4 + f) * 64 + lane) * 8);
            bias = *(const f32x4*)(kb + n * 64 + f * 16 + kg * 4);
        }

        // ---- rotate pipeline
        cb = nb; cc_ = nc_; cbase = nbase; cpm = npm;
        nb = fb; nc_ = fc_; nbase = fbase; npm = fpm; nps = fps;
        inf2 = inf3;
        cur ^= 1;
        __builtin_amdgcn_s_barrier();     // old buf reads done before next overwrite
    }

    // ---- final stats flush
    #pragma unroll
    for (int m = 1; m < 16; m <<= 1) {
        #pragma unroll
        for (int r = 0; r < 4; ++r) {
            s1[r] += __shfl_xor(s1[r], m, 64);
            s2[r] += __shfl_xor(s2[r], m, 64);
        }
    }
    if (l15 == 0) {
        #pragma unroll
        for (int r = 0; r < 4; ++r) {
            int ch = f * 16 + kg * 4 + r;
            atomicAdd(&sums[b * 64 + ch],       s1[r]);
            atomicAdd(&sums[512 + b * 64 + ch], s2[r]);
        }
    }
    #undef STAGE
    #undef DECODE
}

// ---------------------------------------------------------------- K3:
// contiguous bf16 Yc rows -> LDS transpose -> normalized coalesced NCHW f32 store
__global__ void k_final(const unsigned short* __restrict__ Yc, const float* __restrict__ sums,
                        const float* __restrict__ gamma, const float* __restrict__ beta,
                        float* __restrict__ out) {
    __shared__ float ld[128][66];
    __shared__ float smu[64], srs[64], sg[64], sb[64];
    int t = threadIdx.x;
    int b = blockIdx.y, hw0 = blockIdx.x * 128;
    if (t < 64) {
        float mu = sums[b * 64 + t] * (1.0f / HW);
        float vr = sums[512 + b * 64 + t] * (1.0f / HW) - mu * mu;
        smu[t] = mu;
        srs[t] = rsqrtf(fmaxf(vr, 0.0f) + 1e-5f);
        sg[t] = gamma[t]; sb[t] = beta[t];
    }
    int i = t >> 1, half = t & 1;
    const short8* row = (const short8*)(Yc + (((size_t)(b * HW + hw0 + i)) << 6) + half * 32);
    #pragma unroll
    for (int q = 0; q < 4; ++q) {
        short8 v = row[q];
        #pragma unroll
        for (int j = 0; j < 8; ++j)
            ld[i][half * 32 + q * 8 + j] = bf2f((unsigned short)v[j]);
    }
    __syncthreads();
    #pragma unroll
    for (int rep = 0; rep < 32; ++rep) {
        int idx = rep * 256 + t;          // 8192 = 64c x 128hw
        int c = idx >> 7, j = idx & 127;
        float v = (ld[j][c] - smu[c]) * srs[c] * sg[c] + sb[c];
        out[(((size_t)b * 64 + c) << 14) + hw0 + j] = v;
    }
}

extern "C" void kernel_launch(void* const* d_in, const int* in_sizes, int n_in,
                              void* d_out, int out_size, void* d_ws, size_t ws_size,
                              hipStream_t stream) {
    const float* x    = (const float*)d_in[0];
    const float* kw   = (const float*)d_in[1];
    const float* kb   = (const float*)d_in[2];
    const float* w1   = (const float*)d_in[3];
    const float* b1   = (const float*)d_in[4];
    const float* w2   = (const float*)d_in[5];
    const float* b2   = (const float*)d_in[6];
    const float* gam  = (const float*)d_in[7];
    const float* bet  = (const float*)d_in[8];
    float* out = (float*)d_out;

    char* ws = (char*)d_ws;
    unsigned* gcnt      = (unsigned*)(ws + 0);            // 72 u32
    unsigned* ctot      = (unsigned*)(ws + 512);          // 1 u32
    float*    sums      = (float*)   (ws + 4096);         // 1024 f32
    unsigned long long* chunkinfo = (unsigned long long*)(ws + 16384); // 8192 u64 (64 KB)
    unsigned* lists     = (unsigned*)(ws + 131072);       // 72*16384 u32 (4.72 MB)
    unsigned short* Yc  = (unsigned short*)(ws + 5242880);   // 16.78 MB bf16
    unsigned short* Xb  = (unsigned short*)(ws + 22020096);  // 16.78 MB bf16
    unsigned short* WbF = (unsigned short*)(ws + 38797312);  // 0.66 MB
    // total ws usage ~39.5 MB

    hipMemsetAsync(ws, 0, 8192, stream);    // gcnt + ctot + sums
    k_pre<<<337, 256, 0, stream>>>(x, w1, b1, w2, b2, kw, gcnt, lists, Xb, WbF);
    k_prefix<<<1, 256, 0, stream>>>(gcnt, chunkinfo, ctot);
    k_conv<<<NBLK, 512, 0, stream>>>(Xb, WbF, kb, lists, chunkinfo, ctot, Yc, sums);
    k_final<<<dim3(128, 8), 256, 0, stream>>>(Yc, sums, gam, bet, out);
}